// Round 5
// baseline (471.137 us; speedup 1.0000x reference)
//
#include <hip/hip_runtime.h>
#include <math.h>
#include <stdint.h>

#define B 32
#define NTOK 16384
#define DIM 64
#define NS 8
#define HID 128
#define BPB 32                  // blocks per batch
#define JPB 512                 // tokens per block
#define NWAVE 4
#define JPW 128                 // tokens per wave
#define CHUNKS 4                // 4 chunks of 32 tokens per wave
#define PARTF2 520              // l[8] + acc[8*64]
#define SCALE 0.125f
#define EPSA 1e-8f
#define LNEPS 1e-5f
#define SUMATTN (1.0f + (float)NTOK*EPSA)

typedef unsigned short ushort_t;
typedef __attribute__((ext_vector_type(8))) short bf16x8;
typedef __attribute__((ext_vector_type(4))) float f32x4;
typedef __attribute__((ext_vector_type(2))) unsigned int uint2v;

union U4H8 { uint4 u; bf16x8 h; };

__device__ __forceinline__ ushort_t f2bf(float f) {
  unsigned u = __float_as_uint(f);
  unsigned r = (u + 0x7fffu + ((u >> 16) & 1u)) >> 16;
  return (ushort_t)r;
}

__device__ __forceinline__ unsigned cvt_pk_bf16(float lo, float hi) {
  unsigned r;
  asm volatile("v_cvt_pk_bf16_f32 %0, %1, %2" : "=v"(r) : "v"(lo), "v"(hi));
  return r;
}

#define DS_TR(dst, addr, off) \
  asm volatile("ds_read_b64_tr_b16 %0, %1 offset:" #off : "=v"(dst) : "v"(addr))

// --- shared-memory phase overlays -----------------------------------------
struct UpdSh {
  float sL[NS];
  float sUX[NS][DIM], sUpd[NS][DIM];
  float sGx[NS][3*DIM], sGh[NS][3*DIM];
  float sH[NS][DIM], sHln[NS][DIM], sPrev[NS][DIM];
  float sMu[NS], sRs[NS];
  float sM1[NS][HID];
  float sFin[NS][DIM], sS2[NS][DIM], sQ2[NS][DIM];
};
struct FlSh {
  ushort_t lbuf[NWAVE][2048];
  float sPart[NWAVE][PARTF2];
  float sXs[NWAVE][DIM];
};
#define MAXSH ((sizeof(UpdSh) > sizeof(FlSh)) ? sizeof(UpdSh) : sizeof(FlSh))

// ---------------------------------------------------------------------------
// do_update: merge partials -> GRU + residual MLP -> new slots (per-block
// redundant, bit-identical across blocks). Optionally emits qp/c for the
// flash phase and stores slots for the next kernel (blk==0 only).
// ---------------------------------------------------------------------------
__device__ __forceinline__ void do_update(
    const float* __restrict__ Pb, const float* __restrict__ prev,
    const float* __restrict__ xsp_b,
    const float* __restrict__ ln_ff_g, const float* __restrict__ ln_ff_b,
    const float* __restrict__ Wv, const float* __restrict__ bv,
    const float* __restrict__ W_ih, const float* __restrict__ b_ih,
    const float* __restrict__ W_hh, const float* __restrict__ b_hh,
    const float* __restrict__ W1, const float* __restrict__ b1,
    const float* __restrict__ W2, const float* __restrict__ b2,
    const float* __restrict__ Wq, const float* __restrict__ bq,
    const float* __restrict__ Wk, const float* __restrict__ bk,
    const float* __restrict__ ln_s_g, const float* __restrict__ ln_s_b,
    float* __restrict__ slots_store, int do_qp,
    ushort_t* sQp, float* sC, float* sXsum, UpdSh& U, int t)
{
  for (int o = t; o < NS*DIM; o += 256) ((float*)U.sPrev)[o] = prev[o];
  if (t < DIM) {
    float a = 0.f;
    for (int p = 0; p < BPB; ++p) a += xsp_b[(size_t)p*DIM + t];
    sXsum[t] = a;
  }
  if (t >= 128 && t < 136) {
    int i = t - 128;
    float ll = 0.f;
    for (int p = 0; p < BPB; ++p) ll += Pb[p*PARTF2 + i];
    U.sL[i] = ll;
  }
  __syncthreads();
  for (int o = t; o < NS*DIM; o += 256) {
    int i = o >> 6, d = o & 63;
    float a = 0.f;
    for (int p = 0; p < BPB; ++p) a += Pb[p*PARTF2 + 8 + o];
    U.sUX[i][d] = a/U.sL[i] + EPSA*sXsum[d];
  }
  __syncthreads();
  for (int o = t; o < NS*DIM; o += 256) {
    int i = o >> 6, e = o & 63;
    float a = bv[e]*SUMATTN;
    const float* wr = Wv + e*DIM;
    for (int d = 0; d < DIM; ++d) a = fmaf(U.sUX[i][d], wr[d], a);
    U.sUpd[i][e] = a;
  }
  __syncthreads();
  for (int o = t; o < NS*3*DIM; o += 256) {
    int i = o/(3*DIM), oo = o%(3*DIM);
    float ax = b_ih[oo], ah = b_hh[oo];
    const float* wx = W_ih + oo*DIM;
    const float* wh = W_hh + oo*DIM;
    for (int e = 0; e < DIM; ++e) {
      ax = fmaf(U.sUpd[i][e], wx[e], ax);
      ah = fmaf(U.sPrev[i][e], wh[e], ah);
    }
    U.sGx[i][oo] = ax; U.sGh[i][oo] = ah;
  }
  __syncthreads();
  for (int o = t; o < NS*DIM; o += 256) {
    int i = o >> 6, e = o & 63;
    float r = 1.0f/(1.0f + __expf(-(U.sGx[i][e] + U.sGh[i][e])));
    float z = 1.0f/(1.0f + __expf(-(U.sGx[i][DIM+e] + U.sGh[i][DIM+e])));
    float n = tanhf(U.sGx[i][2*DIM+e] + r*U.sGh[i][2*DIM+e]);
    U.sH[i][e] = (1.0f - z)*n + z*U.sPrev[i][e];
  }
  __syncthreads();
  if (t < NS) {
    float s1 = 0.f, s2 = 0.f;
    for (int d = 0; d < DIM; ++d) { float v = U.sH[t][d]; s1 += v; s2 += v*v; }
    float mu = s1*(1.0f/DIM);
    float var = s2*(1.0f/DIM) - mu*mu;
    U.sMu[t] = mu; U.sRs[t] = rsqrtf(var + LNEPS);
  }
  __syncthreads();
  for (int o = t; o < NS*DIM; o += 256) {
    int i = o >> 6, d = o & 63;
    U.sHln[i][d] = (U.sH[i][d]-U.sMu[i])*U.sRs[i]*ln_ff_g[d] + ln_ff_b[d];
  }
  __syncthreads();
  for (int o = t; o < NS*HID; o += 256) {
    int i = o >> 7, h = o & 127;
    float a = b1[h];
    const float* wr = W1 + h*DIM;
    for (int d = 0; d < DIM; ++d) a = fmaf(U.sHln[i][d], wr[d], a);
    U.sM1[i][h] = fmaxf(a, 0.0f);
  }
  __syncthreads();
  for (int o = t; o < NS*DIM; o += 256) {
    int i = o >> 6, e = o & 63;
    float a = b2[e];
    const float* wr = W2 + e*HID;
    for (int h = 0; h < HID; ++h) a = fmaf(U.sM1[i][h], wr[h], a);
    float fin = U.sH[i][e] + a;
    U.sFin[i][e] = fin;
    if (slots_store) slots_store[o] = fin;
  }
  if (do_qp) {
    __syncthreads();
    if (t < NS) {
      float s1 = 0.f, s2 = 0.f;
      for (int d = 0; d < DIM; ++d) { float v = U.sFin[t][d]; s1 += v; s2 += v*v; }
      float mu = s1*(1.0f/DIM);
      float var = s2*(1.0f/DIM) - mu*mu;
      U.sMu[t] = mu; U.sRs[t] = rsqrtf(var + LNEPS);
    }
    __syncthreads();
    for (int o = t; o < NS*DIM; o += 256) {
      int i = o >> 6, d = o & 63;
      U.sS2[i][d] = (U.sFin[i][d]-U.sMu[i])*U.sRs[i]*ln_s_g[d] + ln_s_b[d];
    }
    __syncthreads();
    for (int o = t; o < NS*DIM; o += 256) {
      int i = o >> 6, e = o & 63;
      float a = bq[e];
      const float* wr = Wq + e*DIM;
      for (int d = 0; d < DIM; ++d) a = fmaf(U.sS2[i][d], wr[d], a);
      U.sQ2[i][e] = a;
    }
    __syncthreads();
    for (int o = t; o < NS*DIM; o += 256) {
      int i = o >> 6, d = o & 63;
      float a = 0.f;
      for (int e = 0; e < DIM; ++e) a = fmaf(U.sQ2[i][e], Wk[e*DIM + d], a);
      sQp[o] = f2bf(a*SCALE);
    }
    for (int o = t; o < NS*DIM; o += 256) sQp[512 + o] = 0;
    if (t < NS) {
      float a = 0.f;
      for (int e = 0; e < DIM; ++e) a = fmaf(U.sQ2[t][e], bk[e], a);
      sC[t] = a*SCALE;
    }
  }
}

// qp from the raw initial slots (iteration 0)
__device__ __forceinline__ void qp0(
    const float* __restrict__ slots_b,
    const float* __restrict__ ln_s_g, const float* __restrict__ ln_s_b,
    const float* __restrict__ Wq, const float* __restrict__ bq,
    const float* __restrict__ Wk, const float* __restrict__ bk,
    ushort_t* sQp, float* sC, UpdSh& U, int t)
{
  if (t < NS) {
    const float* sr = slots_b + (size_t)t*DIM;
    float s1 = 0.f, s2 = 0.f;
    for (int d = 0; d < DIM; ++d) { float v = sr[d]; s1 += v; s2 += v*v; }
    float mu = s1*(1.0f/DIM);
    float var = s2*(1.0f/DIM) - mu*mu;
    float rs = rsqrtf(var + LNEPS);
    for (int d = 0; d < DIM; ++d) U.sS2[t][d] = (sr[d]-mu)*rs*ln_s_g[d] + ln_s_b[d];
  }
  __syncthreads();
  for (int o = t; o < NS*DIM; o += 256) {
    int i = o >> 6, e = o & 63;
    float a = bq[e];
    const float* wr = Wq + e*DIM;
    for (int d = 0; d < DIM; ++d) a = fmaf(U.sS2[i][d], wr[d], a);
    U.sQ2[i][e] = a;
  }
  __syncthreads();
  for (int o = t; o < NS*DIM; o += 256) {
    int i = o >> 6, d = o & 63;
    float a = 0.f;
    for (int e = 0; e < DIM; ++e) a = fmaf(U.sQ2[i][e], Wk[e*DIM + d], a);
    sQp[o] = f2bf(a*SCALE);
  }
  for (int o = t; o < NS*DIM; o += 256) sQp[512 + o] = 0;
  if (t < NS) {
    float a = 0.f;
    for (int e = 0; e < DIM; ++e) a = fmaf(U.sQ2[t][e], bk[e], a);
    sC[t] = a*SCALE;
  }
}

// ---------------------------------------------------------------------------
// k_flash<MODE>: MODE 0: qp0 + fused LN flash (writes xln bf16, xsp).
// MODE 1: inline update (prev+partials_in) + flash over xln.
// MODE 2: MODE1 + store exp(dots) into d_out attn region.
// ---------------------------------------------------------------------------
template<int MODE>
__global__ __launch_bounds__(256) void k_flash(
    const float* __restrict__ xf32, ushort_t* __restrict__ xlnb,
    const float* __restrict__ slots_in,
    const float* __restrict__ partials_in, float* __restrict__ partials_out,
    float* __restrict__ xsp, float* __restrict__ slots_store,
    float* __restrict__ dots_out,
    const float* __restrict__ ln_in_g, const float* __restrict__ ln_in_b,
    const float* __restrict__ ln_s_g, const float* __restrict__ ln_s_b,
    const float* __restrict__ ln_ff_g, const float* __restrict__ ln_ff_b,
    const float* __restrict__ Wq, const float* __restrict__ bq,
    const float* __restrict__ Wk, const float* __restrict__ bk,
    const float* __restrict__ Wv, const float* __restrict__ bv,
    const float* __restrict__ W_ih, const float* __restrict__ b_ih,
    const float* __restrict__ W_hh, const float* __restrict__ b_hh,
    const float* __restrict__ W1, const float* __restrict__ b1,
    const float* __restrict__ W2, const float* __restrict__ b2)
{
  __shared__ alignas(16) unsigned char shraw[MAXSH];
  __shared__ ushort_t sQp[16*DIM];
  __shared__ float sC[NS], sXsum[DIM];
  UpdSh& U = *(UpdSh*)shraw;
  FlSh&  F = *(FlSh*)shraw;

  const int b = blockIdx.x >> 5, blk = blockIdx.x & 31;
  const int t = threadIdx.x, w = t >> 6, lane = t & 63;
  const int c = lane & 15, g = lane >> 4;
  const int j0 = blk*JPB + w*JPW;

  const ushort_t* xb  = (MODE != 0) ? (xlnb + ((size_t)b*NTOK + j0)*DIM) : nullptr;
  const float*    xfb = (MODE == 0) ? (xf32 + ((size_t)b*NTOK + j0)*DIM) : nullptr;
  ushort_t*       xob = (MODE == 0) ? (xlnb + ((size_t)b*NTOK + j0)*DIM) : nullptr;

  // T14: issue first-chunk loads before the update phase (hides HBM latency)
  uint4 a00, a01, a10, a11;
  if (MODE != 0) {
    a00 = *(const uint4*)(xb + c*DIM + g*8);
    a01 = *(const uint4*)(xb + c*DIM + g*8 + 32);
    a10 = *(const uint4*)(xb + (16 + c)*DIM + g*8);
    a11 = *(const uint4*)(xb + (16 + c)*DIM + g*8 + 32);
  }

  if (MODE == 0) {
    qp0(slots_in + (size_t)b*NS*DIM, ln_s_g, ln_s_b, Wq, bq, Wk, bk, sQp, sC, U, t);
  } else {
    do_update(partials_in + (size_t)b*BPB*PARTF2, slots_in + (size_t)b*NS*DIM,
              xsp + (size_t)b*BPB*DIM,
              ln_ff_g, ln_ff_b, Wv, bv, W_ih, b_ih, W_hh, b_hh, W1, b1, W2, b2,
              Wq, bq, Wk, bk, ln_s_g, ln_s_b,
              (blk == 0) ? (slots_store + (size_t)b*NS*DIM) : nullptr, 1,
              sQp, sC, sXsum, U, t);
  }
  __syncthreads();

  U4H8 bq0, bq1;
  bq0.u = *(const uint4*)&sQp[c*DIM + g*8];
  bq1.u = *(const uint4*)&sQp[c*DIM + g*8 + 32];
  const float cb_l = (c < NS) ? sC[c] : 0.0f;

  float gl[8], bl_[8], gh[8], bh[8], xs_lo[8], xs_hi[8];
  if (MODE == 0) {
    #pragma unroll
    for (int dd = 0; dd < 8; ++dd) {
      gl[dd] = ln_in_g[g*8 + dd];       bl_[dd] = ln_in_b[g*8 + dd];
      gh[dd] = ln_in_g[g*8 + 32 + dd];  bh[dd]  = ln_in_b[g*8 + 32 + dd];
      xs_lo[dd] = 0.f; xs_hi[dd] = 0.f;
    }
  }

  f32x4 acc0 = {0,0,0,0}, acc1 = {0,0,0,0}, acc2 = {0,0,0,0}, acc3 = {0,0,0,0};
  float lp = 0.0f;

  const unsigned lds0 = (unsigned)(uintptr_t)&F.lbuf[w][0];
  const unsigned trb = lds0 + (unsigned)(g*1024 + c*2);

  const int T0 = c, T1 = 16 + c;
  const int e00 = ((T0>>2)*4 + (g>>1)    )*64 + (T0&3)*16 + (g&1)*8;
  const int e01 = ((T0>>2)*4 + (g>>1) + 2)*64 + (T0&3)*16 + (g&1)*8;
  const int e10 = ((T1>>2)*4 + (g>>1)    )*64 + (T1&3)*16 + (g&1)*8;
  const int e11 = ((T1>>2)*4 + (g>>1) + 2)*64 + (T1&3)*16 + (g&1)*8;

  const int s0 = ((g & 1) << 5) + c;
  const bool til1 = (g >= 2);

  #pragma unroll
  for (int ch = 0; ch < CHUNKS; ++ch) {
    if (MODE == 0) {
      const float* xt = xfb + (size_t)ch*32*DIM;
      {
        const float* r = xt + T0*DIM + g*8;
        float4 q0 = *(const float4*)(r);
        float4 q1 = *(const float4*)(r + 4);
        float4 q2 = *(const float4*)(r + 32);
        float4 q3 = *(const float4*)(r + 36);
        float v[16] = {q0.x,q0.y,q0.z,q0.w, q1.x,q1.y,q1.z,q1.w,
                       q2.x,q2.y,q2.z,q2.w, q3.x,q3.y,q3.z,q3.w};
        float s1 = 0.f, s2 = 0.f;
        #pragma unroll
        for (int k = 0; k < 16; ++k) { s1 += v[k]; s2 = fmaf(v[k], v[k], s2); }
        s1 += __shfl_xor(s1, 16); s2 += __shfl_xor(s2, 16);
        s1 += __shfl_xor(s1, 32); s2 += __shfl_xor(s2, 32);
        float mu = s1*(1.0f/DIM);
        float var = s2*(1.0f/DIM) - mu*mu;
        float rs = rsqrtf(var + LNEPS);
        float xl[16];
        #pragma unroll
        for (int dd = 0; dd < 8; ++dd) {
          xl[dd]   = (v[dd]  -mu)*rs*gl[dd] + bl_[dd]; xs_lo[dd] += xl[dd];
          xl[8+dd] = (v[8+dd]-mu)*rs*gh[dd] + bh[dd];  xs_hi[dd] += xl[8+dd];
        }
        a00 = make_uint4(cvt_pk_bf16(xl[0],xl[1]),  cvt_pk_bf16(xl[2],xl[3]),
                         cvt_pk_bf16(xl[4],xl[5]),  cvt_pk_bf16(xl[6],xl[7]));
        a01 = make_uint4(cvt_pk_bf16(xl[8],xl[9]),  cvt_pk_bf16(xl[10],xl[11]),
                         cvt_pk_bf16(xl[12],xl[13]),cvt_pk_bf16(xl[14],xl[15]));
        *(uint4*)(xob + (size_t)(ch*32 + T0)*DIM + g*8)      = a00;
        *(uint4*)(xob + (size_t)(ch*32 + T0)*DIM + g*8 + 32) = a01;
      }
      {
        const float* r = xt + T1*DIM + g*8;
        float4 q0 = *(const float4*)(r);
        float4 q1 = *(const float4*)(r + 4);
        float4 q2 = *(const float4*)(r + 32);
        float4 q3 = *(const float4*)(r + 36);
        float v[16] = {q0.x,q0.y,q0.z,q0.w, q1.x,q1.y,q1.z,q1.w,
                       q2.x,q2.y,q2.z,q2.w, q3.x,q3.y,q3.z,q3.w};
        float s1 = 0.f, s2 = 0.f;
        #pragma unroll
        for (int k = 0; k < 16; ++k) { s1 += v[k]; s2 = fmaf(v[k], v[k], s2); }
        s1 += __shfl_xor(s1, 16); s2 += __shfl_xor(s2, 16);
        s1 += __shfl_xor(s1, 32); s2 += __shfl_xor(s2, 32);
        float mu = s1*(1.0f/DIM);
        float var = s2*(1.0f/DIM) - mu*mu;
        float rs = rsqrtf(var + LNEPS);
        float xl[16];
        #pragma unroll
        for (int dd = 0; dd < 8; ++dd) {
          xl[dd]   = (v[dd]  -mu)*rs*gl[dd] + bl_[dd]; xs_lo[dd] += xl[dd];
          xl[8+dd] = (v[8+dd]-mu)*rs*gh[dd] + bh[dd];  xs_hi[dd] += xl[8+dd];
        }
        a10 = make_uint4(cvt_pk_bf16(xl[0],xl[1]),  cvt_pk_bf16(xl[2],xl[3]),
                         cvt_pk_bf16(xl[4],xl[5]),  cvt_pk_bf16(xl[6],xl[7]));
        a11 = make_uint4(cvt_pk_bf16(xl[8],xl[9]),  cvt_pk_bf16(xl[10],xl[11]),
                         cvt_pk_bf16(xl[12],xl[13]),cvt_pk_bf16(xl[14],xl[15]));
        *(uint4*)(xob + (size_t)(ch*32 + T1)*DIM + g*8)      = a10;
        *(uint4*)(xob + (size_t)(ch*32 + T1)*DIM + g*8 + 32) = a11;
      }
    }

    *(uint4*)&F.lbuf[w][e00] = a00;
    *(uint4*)&F.lbuf[w][e01] = a01;
    *(uint4*)&F.lbuf[w][e10] = a10;
    *(uint4*)&F.lbuf[w][e11] = a11;

    uint4 n00, n01, n10, n11;
    if (MODE != 0 && ch + 1 < CHUNKS) {
      const ushort_t* xn = xb + (size_t)(ch + 1)*32*DIM;
      n00 = *(const uint4*)(xn + c*DIM + g*8);
      n01 = *(const uint4*)(xn + c*DIM + g*8 + 32);
      n10 = *(const uint4*)(xn + (16 + c)*DIM + g*8);
      n11 = *(const uint4*)(xn + (16 + c)*DIM + g*8 + 32);
    }

    f32x4 d0 = {0,0,0,0}, d1 = {0,0,0,0};
    { U4H8 A; A.u = a00; d0 = __builtin_amdgcn_mfma_f32_16x16x32_bf16(A.h, bq0.h, d0, 0,0,0); }
    { U4H8 A; A.u = a01; d0 = __builtin_amdgcn_mfma_f32_16x16x32_bf16(A.h, bq1.h, d0, 0,0,0); }
    { U4H8 A; A.u = a10; d1 = __builtin_amdgcn_mfma_f32_16x16x32_bf16(A.h, bq0.h, d1, 0,0,0); }
    { U4H8 A; A.u = a11; d1 = __builtin_amdgcn_mfma_f32_16x16x32_bf16(A.h, bq1.h, d1, 0,0,0); }

    float p00 = __expf(d0[0] + cb_l), p01 = __expf(d0[1] + cb_l);
    float p02 = __expf(d0[2] + cb_l), p03 = __expf(d0[3] + cb_l);
    float p10 = __expf(d1[0] + cb_l), p11 = __expf(d1[1] + cb_l);
    float p12 = __expf(d1[2] + cb_l), p13 = __expf(d1[3] + cb_l);
    lp += p00 + p01 + p02 + p03 + p10 + p11 + p12 + p13;

    if (MODE == 2 && c < NS) {
      float* dp = dots_out + ((size_t)(b*NS + c))*NTOK + j0 + ch*32 + g*4;
      *(float4*)dp        = make_float4(p00, p01, p02, p03);
      *(float4*)(dp + 16) = make_float4(p10, p11, p12, p13);
    }

    unsigned pk00 = cvt_pk_bf16(p00, p01), pk01 = cvt_pk_bf16(p02, p03);
    unsigned pk10 = cvt_pk_bf16(p10, p11), pk11 = cvt_pk_bf16(p12, p13);
    unsigned b0a = (unsigned)__shfl((int)pk00, s0),      b0b = (unsigned)__shfl((int)pk10, s0);
    unsigned b1a = (unsigned)__shfl((int)pk01, s0),      b1b = (unsigned)__shfl((int)pk11, s0);
    unsigned b2a = (unsigned)__shfl((int)pk00, s0 + 16), b2b = (unsigned)__shfl((int)pk10, s0 + 16);
    unsigned b3a = (unsigned)__shfl((int)pk01, s0 + 16), b3b = (unsigned)__shfl((int)pk11, s0 + 16);
    U4H8 PB;
    PB.u = make_uint4(til1 ? b0b : b0a, til1 ? b1b : b1a,
                      til1 ? b2b : b2a, til1 ? b3b : b3a);

    asm volatile("s_waitcnt lgkmcnt(0)" ::: "memory");
    __builtin_amdgcn_sched_barrier(0);
    uint2v r0, r1, r2, r3, r4, r5, r6, r7;
    DS_TR(r0, trb, 0);   DS_TR(r1, trb, 512);
    DS_TR(r2, trb, 128); DS_TR(r3, trb, 640);
    DS_TR(r4, trb, 256); DS_TR(r5, trb, 768);
    DS_TR(r6, trb, 384); DS_TR(r7, trb, 896);
    asm volatile("s_waitcnt lgkmcnt(0)" ::: "memory");
    __builtin_amdgcn_sched_barrier(0);
    U4H8 X0, X1, X2, X3;
    X0.u = make_uint4(r0.x, r0.y, r1.x, r1.y);
    X1.u = make_uint4(r2.x, r2.y, r3.x, r3.y);
    X2.u = make_uint4(r4.x, r4.y, r5.x, r5.y);
    X3.u = make_uint4(r6.x, r6.y, r7.x, r7.y);
    acc0 = __builtin_amdgcn_mfma_f32_16x16x32_bf16(X0.h, PB.h, acc0, 0,0,0);
    acc1 = __builtin_amdgcn_mfma_f32_16x16x32_bf16(X1.h, PB.h, acc1, 0,0,0);
    acc2 = __builtin_amdgcn_mfma_f32_16x16x32_bf16(X2.h, PB.h, acc2, 0,0,0);
    acc3 = __builtin_amdgcn_mfma_f32_16x16x32_bf16(X3.h, PB.h, acc3, 0,0,0);

    if (MODE != 0) { a00 = n00; a01 = n01; a10 = n10; a11 = n11; }
  }

  lp += __shfl_xor(lp, 16);
  lp += __shfl_xor(lp, 32);

  if (c < NS) {
    if (g == 0) F.sPart[w][c] = lp;
    #pragma unroll
    for (int r = 0; r < 4; ++r) F.sPart[w][8 + c*64 +  0 + g*4 + r] = acc0[r];
    #pragma unroll
    for (int r = 0; r < 4; ++r) F.sPart[w][8 + c*64 + 16 + g*4 + r] = acc1[r];
    #pragma unroll
    for (int r = 0; r < 4; ++r) F.sPart[w][8 + c*64 + 32 + g*4 + r] = acc2[r];
    #pragma unroll
    for (int r = 0; r < 4; ++r) F.sPart[w][8 + c*64 + 48 + g*4 + r] = acc3[r];
  }
  if (MODE == 0) {
    #pragma unroll
    for (int stepi = 0; stepi < 4; ++stepi) {
      const int mask = 1 << stepi;
      #pragma unroll
      for (int dd = 0; dd < 8; ++dd) {
        xs_lo[dd] += __shfl_xor(xs_lo[dd], mask);
        xs_hi[dd] += __shfl_xor(xs_hi[dd], mask);
      }
    }
    if (c == 0) {
      #pragma unroll
      for (int dd = 0; dd < 8; ++dd) {
        F.sXs[w][g*8 + dd]      = xs_lo[dd];
        F.sXs[w][g*8 + 32 + dd] = xs_hi[dd];
      }
    }
  }
  __syncthreads();
  float* P = partials_out + (size_t)blockIdx.x * PARTF2;
  for (int o = t; o < PARTF2; o += 256)
    P[o] = F.sPart[0][o] + F.sPart[1][o] + F.sPart[2][o] + F.sPart[3][o];
  if (MODE == 0 && t < DIM)
    xsp[(size_t)blockIdx.x*DIM + t] = F.sXs[0][t] + F.sXs[1][t] + F.sXs[2][t] + F.sXs[3][t];
}

// ---------------------------------------------------------------------------
// k_fin: scale exp-dots by 1/l (+EPS) in place; blk==0 does the final slot
// update (iter-2 partials) and writes final slots.
// ---------------------------------------------------------------------------
__global__ __launch_bounds__(256) void k_fin(
    const float* __restrict__ partials, const float* __restrict__ prev,
    const float* __restrict__ xsp,
    float* __restrict__ out, float* __restrict__ outslots,
    const float* __restrict__ ln_ff_g, const float* __restrict__ ln_ff_b,
    const float* __restrict__ ln_s_g, const float* __restrict__ ln_s_b,
    const float* __restrict__ Wq, const float* __restrict__ bq,
    const float* __restrict__ Wk, const float* __restrict__ bk,
    const float* __restrict__ Wv, const float* __restrict__ bv,
    const float* __restrict__ W_ih, const float* __restrict__ b_ih,
    const float* __restrict__ W_hh, const float* __restrict__ b_hh,
    const float* __restrict__ W1, const float* __restrict__ b1,
    const float* __restrict__ W2, const float* __restrict__ b2)
{
  __shared__ alignas(16) unsigned char shraw[sizeof(UpdSh)];
  __shared__ float sLi[NS], sXsum[DIM];
  __shared__ ushort_t sQp[16*DIM];
  __shared__ float sC[NS];
  UpdSh& U = *(UpdSh*)shraw;

  const int b = blockIdx.x >> 5, blk = blockIdx.x & 31;
  const int t = threadIdx.x;
  const float* Pb = partials + (size_t)b*BPB*PARTF2;

  if (t < NS) {
    float ll = 0.f;
    for (int p = 0; p < BPB; ++p) ll += Pb[p*PARTF2 + t];
    sLi[t] = 1.0f/ll;
  }
  __syncthreads();
  // scale this block's strip: 8 rows x 512 cols
  for (int idx = t; idx < 1024; idx += 256) {
    int r = idx >> 7, c4 = idx & 127;
    float4* p = (float4*)out + ((size_t)(b*NS + r))*(NTOK/4) + blk*(JPB/4) + c4;
    float4 v = *p;
    float li = sLi[r];
    v.x = v.x*li + EPSA; v.y = v.y*li + EPSA;
    v.z = v.z*li + EPSA; v.w = v.w*li + EPSA;
    *p = v;
  }
  if (blk == 0) {
    do_update(Pb, prev + (size_t)b*NS*DIM, xsp + (size_t)b*BPB*DIM,
              ln_ff_g, ln_ff_b, Wv, bv, W_ih, b_ih, W_hh, b_hh, W1, b1, W2, b2,
              Wq, bq, Wk, bk, ln_s_g, ln_s_b,
              outslots + (size_t)b*NS*DIM, 0, sQp, sC, sXsum, U, t);
  }
}

extern "C" void kernel_launch(void* const* d_in, const int* in_sizes, int n_in,
                              void* d_out, int out_size, void* d_ws, size_t ws_size,
                              hipStream_t stream)
{
  const float* x       = (const float*)d_in[0];
  const float* slots0  = (const float*)d_in[1];
  const float* ln_in_g = (const float*)d_in[2];
  const float* ln_in_b = (const float*)d_in[3];
  const float* ln_s_g  = (const float*)d_in[4];
  const float* ln_s_b  = (const float*)d_in[5];
  const float* ln_ff_g = (const float*)d_in[6];
  const float* ln_ff_b = (const float*)d_in[7];
  const float* Wq = (const float*)d_in[8];
  const float* bq = (const float*)d_in[9];
  const float* Wk = (const float*)d_in[10];
  const float* bk = (const float*)d_in[11];
  const float* Wv = (const float*)d_in[12];
  const float* bv = (const float*)d_in[13];
  const float* W_ih = (const float*)d_in[14];
  const float* b_ih = (const float*)d_in[15];
  const float* W_hh = (const float*)d_in[16];
  const float* b_hh = (const float*)d_in[17];
  const float* W1 = (const float*)d_in[18];
  const float* b1 = (const float*)d_in[19];
  const float* W2 = (const float*)d_in[20];
  const float* b2 = (const float*)d_in[21];

  float* out = (float*)d_out;
  float* outslots = out + (size_t)B*NS*NTOK;

  float* partialsA = (float*)d_ws;                           // 1024*520
  float* partialsB = partialsA + (size_t)1024*PARTF2;        // 1024*520
  float* xsp    = partialsB + (size_t)1024*PARTF2;           // 1024*64
  float* slotsA = xsp + (size_t)1024*64;                     // 32*512
  float* slotsB = slotsA + (size_t)B*NS*DIM;                 // 32*512
  ushort_t* xlnb = (ushort_t*)(slotsB + (size_t)B*NS*DIM);   // 32*16384*64 bf16

  dim3 grid(B*BPB), blk(256);

  // iter 0: qp from slots0, fused LN flash, writes xln/xsp/partialsA
  k_flash<0><<<grid, blk, 0, stream>>>(x, xlnb, slots0, nullptr, partialsA,
      xsp, nullptr, nullptr,
      ln_in_g, ln_in_b, ln_s_g, ln_s_b, ln_ff_g, ln_ff_b,
      Wq, bq, Wk, bk, Wv, bv, W_ih, b_ih, W_hh, b_hh, W1, b1, W2, b2);
  // iter 1: update(partialsA, slots0)->slots1+qp1, flash -> partialsB
  k_flash<1><<<grid, blk, 0, stream>>>(nullptr, xlnb, slots0, partialsA, partialsB,
      xsp, slotsA, nullptr,
      ln_in_g, ln_in_b, ln_s_g, ln_s_b, ln_ff_g, ln_ff_b,
      Wq, bq, Wk, bk, Wv, bv, W_ih, b_ih, W_hh, b_hh, W1, b1, W2, b2);
  // iter 2: update(partialsB, slots1)->slots2+qp2, flash + exp store -> partialsA
  k_flash<2><<<grid, blk, 0, stream>>>(nullptr, xlnb, slotsA, partialsB, partialsA,
      xsp, slotsB, out,
      ln_in_g, ln_in_b, ln_s_g, ln_s_b, ln_ff_g, ln_ff_b,
      Wq, bq, Wk, bk, Wv, bv, W_ih, b_ih, W_hh, b_hh, W1, b1, W2, b2);
  // finalize: scale attn by 1/l (+EPS); final slot update -> outslots
  k_fin<<<grid, blk, 0, stream>>>(partialsA, slotsB, xsp, out, outslots,
      ln_ff_g, ln_ff_b, ln_s_g, ln_s_b,
      Wq, bq, Wk, bk, Wv, bv, W_ih, b_ih, W_hh, b_hh, W1, b1, W2, b2);
}